// Round 1
// baseline (161.530 us; speedup 1.0000x reference)
//
#include <hip/hip_runtime.h>

#define H 256
#define W 256
#define OH 128
#define OW 128
#define TW 32   // output tile width  (threads x)
#define TH 8    // output tile height (threads y)

// x tile:  rows 2*TH+3 = 19, cols 2*TW+3 = 67  (global rows r0-1 .. r0+2*TH+1, clamped)
// eq4 tile: rows 2*TH+1 = 17, cols 2*TW+1 = 65 (global rows r0 .. r0+2*TH, clamped)

__global__ __launch_bounds__(256)
void dp_fused_kernel(const float* __restrict__ x,
                     const float* __restrict__ lamp,
                     const float* __restrict__ alphap,
                     float* __restrict__ out)
{
    __shared__ float xs[19][68];   // stride 68 to de-phase banks
    __shared__ float e4[17][67];   // stride 67 (odd) to de-phase banks

    const int plane = blockIdx.y;           // b*C + c  (depthwise: planes independent)
    const int tile  = blockIdx.x;           // 0..63
    const int tx0 = (tile & 3) * TW;        // output col origin
    const int ty0 = (tile >> 2) * TH;       // output row origin
    const int r0  = 2 * ty0;                // input-row origin of eq4 tile
    const int c0  = 2 * tx0;

    const float* __restrict__ xp = x + (size_t)plane * (H * W);
    const int tid = threadIdx.x;

    const float la = fabsf(lamp[0]);
    const float al = fabsf(alphap[0]);

    // ---- stage x tile (replicate-clamped) ----
    for (int i = tid; i < 19 * 67; i += 256) {
        int lr = i / 67, lc = i - lr * 67;
        int gr = r0 - 1 + lr; gr = gr < 0 ? 0 : (gr > H - 1 ? H - 1 : gr);
        int gc = c0 - 1 + lc; gc = gc < 0 ? 0 : (gc > W - 1 ? W - 1 : gc);
        xs[lr][lc] = xp[gr * W + gc];
    }
    __syncthreads();

    // ---- compute eq4 tile ----
    for (int i = tid; i < 17 * 65; i += 256) {
        int lr = i / 65, lc = i - lr * 65;
        int gre = r0 + lr; if (gre > H - 1) gre = H - 1;   // bottom-edge replicate
        int gce = c0 + lc; if (gce > W - 1) gce = W - 1;   // right-edge replicate
        int cr = gre - (r0 - 1);   // center row in xs coords (neighbors stay valid)
        int cc = gce - (c0 - 1);
        float m00 = xs[cr - 1][cc - 1], m01 = xs[cr - 1][cc], m02 = xs[cr - 1][cc + 1];
        float m10 = xs[cr    ][cc - 1], m11 = xs[cr    ][cc], m12 = xs[cr    ][cc + 1];
        float m20 = xs[cr + 1][cc - 1], m21 = xs[cr + 1][cc], m22 = xs[cr + 1][cc + 1];
        float blur = (m00 + 2.f * m01 + m02
                      + 2.f * (m10 + 2.f * m11 + m12)
                      + m20 + 2.f * m21 + m22) * (1.f / 16.f);
        float d  = m11 - blur;
        float s  = d * d + 1e-12f;          // (x-eq2)^2 + eps^2
        float s2 = s * s;                   // (...)^2
        float e  = __expf(la * __logf(s2)) + al;   // (...)^lambda + alpha
        e4[lr][lc] = e;
    }
    __syncthreads();

    // ---- per-thread: 4 sub-pixels -> one output ----
    const int txl = tid & 31;   // 0..31
    const int tyl = tid >> 5;   // 0..7
    float e[3][3];
#pragma unroll
    for (int a = 0; a < 3; ++a)
#pragma unroll
        for (int b = 0; b < 3; ++b)
            e[a][b] = e4[2 * tyl + a][2 * txl + b];

    float acc = 0.f;
#pragma unroll
    for (int a = 0; a < 2; ++a)
#pragma unroll
        for (int b = 0; b < 2; ++b) {
            float den = (e[a][b] + e[a][b + 1] + e[a + 1][b] + e[a + 1][b + 1]) * 0.25f + 1e-8f;
            float xv  = xs[2 * tyl + 1 + a][2 * txl + 1 + b];
            acc += xv * e[a][b] / den;
        }
    out[(size_t)plane * (OH * OW) + (size_t)(ty0 + tyl) * OW + (tx0 + txl)] = acc * 0.25f;
}

extern "C" void kernel_launch(void* const* d_in, const int* in_sizes, int n_in,
                              void* d_out, int out_size, void* d_ws, size_t ws_size,
                              hipStream_t stream) {
    const float* x     = (const float*)d_in[0];
    const float* lam   = (const float*)d_in[1];
    const float* alpha = (const float*)d_in[2];
    float* out = (float*)d_out;

    // 16*64 = 1024 planes; 64 tiles of 32x8 outputs per 128x128 output plane
    dim3 grid(64, 1024, 1);
    dim3 block(256, 1, 1);
    dp_fused_kernel<<<grid, block, 0, stream>>>(x, lam, alpha, out);
}

// Round 2
// 79.599 us; speedup vs baseline: 2.0293x; 2.0293x over previous
//
#include <hip/hip_runtime.h>

#define H 256
#define W 256
#define OH 128
#define OW 128
#define RH 16   // output rows per wave strip; 8 strips per plane

// One wave (64 lanes x float4) covers a full 256-wide row.
// Rolling-register walk down the rows: h = horizontal [1,2,1] blur (shfl for
// neighbors), t = vertical [1,2,1] of h, eq4 = ((x - t/16)^2 + 1e-12)^(2|la|)+|al|,
// denom = 2x2 stride-1 avgpool of eq4 (edge-replicated), out = 2x2 stride-2
// avgpool of x*eq4/denom.

__device__ __forceinline__ float4 loadrow(const float* __restrict__ base, int r, int lane) {
    r = r < 0 ? 0 : (r > H - 1 ? H - 1 : r);
    return *reinterpret_cast<const float4*>(base + (size_t)r * W + 4 * lane);
}

__device__ __forceinline__ float4 hblur(const float4 v, int lane) {
    float left  = __shfl_up(v.w, 1);
    float right = __shfl_down(v.x, 1);
    if (lane == 0)  left  = v.x;   // replicate pad col -1 -> col 0
    if (lane == 63) right = v.w;   // replicate pad col 256 -> col 255
    float4 h;
    h.x = __fmaf_rn(2.f, v.x, left) + v.y;
    h.y = __fmaf_rn(2.f, v.y, v.x)  + v.z;
    h.z = __fmaf_rn(2.f, v.z, v.y)  + v.w;
    h.w = __fmaf_rn(2.f, v.w, v.z)  + right;
    return h;
}

__device__ __forceinline__ float eq4s(float xv, float tv, float c2la, float al) {
    float d = __fmaf_rn(tv, -0.0625f, xv);     // x - blur
    float s = __fmaf_rn(d, d, 1e-12f);         // d^2 + eps^2
    return __expf(c2la * __logf(s)) + al;      // (s^2)^la + al  == s^(2 la) + al
}

__global__ __launch_bounds__(256)
void dp_rolling_kernel(const float* __restrict__ x,
                       const float* __restrict__ lamp,
                       const float* __restrict__ alphap,
                       float* __restrict__ out)
{
    const int wid   = threadIdx.x >> 6;
    const int lane  = threadIdx.x & 63;
    const int bid   = blockIdx.x;
    const int plane = bid >> 1;                     // 0..1023 (b*C + c)
    const int strip = ((bid & 1) << 2) | wid;       // 0..7
    const int yb    = strip * RH;                   // output-row origin
    const int r0    = 2 * yb;                       // input-row origin

    const float* __restrict__ xp = x + (size_t)plane * (H * W);
    float* op = out + (size_t)plane * (OH * OW) + (size_t)yb * OW + 2 * lane;

    const float c2la = 2.f * fabsf(lamp[0]);
    const float al   = fabsf(alphap[0]);

    // rolling state (invariant at entry to step(r)):
    //   hm = h[r-1], hc = h[r], xc = x[r], xn = x[r+1],
    //   ep = eq4[r-1], xe = x[r-1]
    float4 hm, hc, xc, xn, ep, xe;
    float accx = 0.f, accy = 0.f;

    // ---- prologue: compute eq4[r0] ----
    {
        float4 va = loadrow(xp, r0 - 1, lane);
        float4 ha = hblur(va, lane);
        float4 vb = loadrow(xp, r0, lane);
        float4 hb = hblur(vb, lane);
        float4 vc = loadrow(xp, r0 + 1, lane);
        float4 hx = hblur(vc, lane);
        float4 t;
        t.x = __fmaf_rn(2.f, hb.x, ha.x) + hx.x;
        t.y = __fmaf_rn(2.f, hb.y, ha.y) + hx.y;
        t.z = __fmaf_rn(2.f, hb.z, ha.z) + hx.z;
        t.w = __fmaf_rn(2.f, hb.w, ha.w) + hx.w;
        ep.x = eq4s(vb.x, t.x, c2la, al);
        ep.y = eq4s(vb.y, t.y, c2la, al);
        ep.z = eq4s(vb.z, t.z, c2la, al);
        ep.w = eq4s(vb.w, t.w, c2la, al);
        xe = vb; hm = hb; hc = hx; xc = vc;
        xn = loadrow(xp, r0 + 2, lane);
    }

    // finish: given ec = eq4[r], produce eq7 row r-1 contribution into acc
    auto finish = [&](const float4 ec) {
        float4 p;
        p.x = ep.x + ec.x; p.y = ep.y + ec.y;
        p.z = ep.z + ec.z; p.w = ep.w + ec.w;
        float pn = __shfl_down(p.x, 1);
        if (lane == 63) pn = p.w;                  // replicate pad col 256
        float d0 = __fmaf_rn(p.x + p.y, 0.25f, 1e-8f);
        float d1 = __fmaf_rn(p.y + p.z, 0.25f, 1e-8f);
        float d2 = __fmaf_rn(p.z + p.w, 0.25f, 1e-8f);
        float d3 = __fmaf_rn(p.w + pn,  0.25f, 1e-8f);
        accx += xe.x * ep.x * __builtin_amdgcn_rcpf(d0)
              + xe.y * ep.y * __builtin_amdgcn_rcpf(d1);
        accy += xe.z * ep.z * __builtin_amdgcn_rcpf(d2)
              + xe.w * ep.w * __builtin_amdgcn_rcpf(d3);
    };

    // full step at input row r (r <= H-1): compute eq4[r], finish row r-1
    auto stepT = [&](int r) {
        float4 xn2 = loadrow(xp, r + 2, lane);     // prefetch (clamped)
        float4 hn  = hblur(xn, lane);              // h[r+1]
        float4 t;
        t.x = __fmaf_rn(2.f, hc.x, hm.x) + hn.x;
        t.y = __fmaf_rn(2.f, hc.y, hm.y) + hn.y;
        t.z = __fmaf_rn(2.f, hc.z, hm.z) + hn.z;
        t.w = __fmaf_rn(2.f, hc.w, hm.w) + hn.w;
        float4 ec;
        ec.x = eq4s(xc.x, t.x, c2la, al);
        ec.y = eq4s(xc.y, t.y, c2la, al);
        ec.z = eq4s(xc.z, t.z, c2la, al);
        ec.w = eq4s(xc.w, t.w, c2la, al);
        finish(ec);
        hm = hc; hc = hn; xe = xc; xc = xn; xn = xn2; ep = ec;
    };

    int r = r0 + 1;
    for (int orr = 0; orr < RH - 1; ++orr) {
        stepT(r); ++r;
        stepT(r); ++r;
        float2 o; o.x = accx * 0.25f; o.y = accy * 0.25f;
        *reinterpret_cast<float2*>(op) = o;
        op += OW;
        accx = 0.f; accy = 0.f;
    }
    // last output row of the strip: second step may be eq4 row 256 -> replicate
    stepT(r); ++r;
    if (r <= H - 1) {
        stepT(r);
    } else {
        finish(ep);                                // ec := ep (bottom replicate)
    }
    float2 o; o.x = accx * 0.25f; o.y = accy * 0.25f;
    *reinterpret_cast<float2*>(op) = o;
}

extern "C" void kernel_launch(void* const* d_in, const int* in_sizes, int n_in,
                              void* d_out, int out_size, void* d_ws, size_t ws_size,
                              hipStream_t stream) {
    const float* x     = (const float*)d_in[0];
    const float* lam   = (const float*)d_in[1];
    const float* alpha = (const float*)d_in[2];
    float* out = (float*)d_out;

    // 1024 planes x 8 strips of 16 output rows; 4 strips (waves) per block
    dim3 grid(2048, 1, 1);
    dim3 block(256, 1, 1);
    dp_rolling_kernel<<<grid, block, 0, stream>>>(x, lam, alpha, out);
}

// Round 4
// 60.323 us; speedup vs baseline: 2.6777x; 1.3196x over previous
//
#include <hip/hip_runtime.h>

#define H 256
#define W 256
#define OH 128
#define OW 128
#define RH 16   // output rows per wave strip; 8 strips per plane

typedef float vfloat2 __attribute__((ext_vector_type(2)));

// One wave (64 lanes x float4) covers a full 256-wide row.
// Rolling-register walk down the rows: h = horizontal [1,2,1] blur (shfl for
// neighbors), t = vertical [1,2,1] of h, eq4 = ((x - t/16)^2 + 1e-12)^(2|la|)+|al|,
// denom = 2x2 stride-1 avgpool of eq4 (edge-replicated), out = 2x2 stride-2
// avgpool of x*eq4/denom.
// 3-deep row prefetch keeps 2 global loads in flight per wave.

__device__ __forceinline__ float4 loadrow(const float* __restrict__ base, int r, int lane) {
    r = r < 0 ? 0 : (r > H - 1 ? H - 1 : r);
    return *reinterpret_cast<const float4*>(base + (size_t)r * W + 4 * lane);
}

__device__ __forceinline__ float4 hblur(const float4 v, int lane) {
    float left  = __shfl_up(v.w, 1);
    float right = __shfl_down(v.x, 1);
    left  = (lane == 0)  ? v.x : left;   // replicate pad col -1 -> col 0
    right = (lane == 63) ? v.w : right;  // replicate pad col 256 -> col 255
    float4 h;
    h.x = __fmaf_rn(2.f, v.x, left) + v.y;
    h.y = __fmaf_rn(2.f, v.y, v.x)  + v.z;
    h.z = __fmaf_rn(2.f, v.z, v.y)  + v.w;
    h.w = __fmaf_rn(2.f, v.w, v.z)  + right;
    return h;
}

// s^(2|la|) + |al|  ==  2^(2|la| * log2(s)) + |al|
// v_log_f32 / v_exp_f32 are natively base-2 on gfx9xx.
__device__ __forceinline__ float eq4s(float xv, float tv, float c2la, float al) {
    float d = __fmaf_rn(tv, -0.0625f, xv);     // x - blur
    float s = __fmaf_rn(d, d, 1e-12f);         // d^2 + eps^2
    return __builtin_amdgcn_exp2f(c2la * __builtin_amdgcn_logf(s)) + al;
}

__global__ __launch_bounds__(256)
void dp_rolling_kernel(const float* __restrict__ x,
                       const float* __restrict__ lamp,
                       const float* __restrict__ alphap,
                       float* __restrict__ out)
{
    const int wid   = threadIdx.x >> 6;
    const int lane  = threadIdx.x & 63;
    const int bid   = blockIdx.x;
    const int plane = bid >> 1;                     // 0..1023 (b*C + c)
    const int strip = ((bid & 1) << 2) | wid;       // 0..7
    const int yb    = strip * RH;                   // output-row origin
    const int r0    = 2 * yb;                       // input-row origin

    const float* __restrict__ xp = x + (size_t)plane * (H * W);
    float* op = out + (size_t)plane * (OH * OW) + (size_t)yb * OW + 2 * lane;

    const float c2la = 2.f * fabsf(lamp[0]);
    const float al   = fabsf(alphap[0]);

    // rolling state (invariant at entry to step(r)):
    //   hm = h[r-1], hc = h[r], xc = x[r], xn = x[r+1], xn2 = x[r+2],
    //   ep = eq4[r-1], xe = x[r-1]
    float4 hm, hc, xc, xn, xn2, ep, xe;
    float accx = 0.f, accy = 0.f;

    // ---- prologue: compute eq4[r0] ----
    {
        float4 va = loadrow(xp, r0 - 1, lane);
        float4 vb = loadrow(xp, r0, lane);
        float4 vc = loadrow(xp, r0 + 1, lane);
        xn  = loadrow(xp, r0 + 2, lane);
        xn2 = loadrow(xp, r0 + 3, lane);
        float4 ha = hblur(va, lane);
        float4 hb = hblur(vb, lane);
        float4 hx = hblur(vc, lane);
        float4 t;
        t.x = __fmaf_rn(2.f, hb.x, ha.x) + hx.x;
        t.y = __fmaf_rn(2.f, hb.y, ha.y) + hx.y;
        t.z = __fmaf_rn(2.f, hb.z, ha.z) + hx.z;
        t.w = __fmaf_rn(2.f, hb.w, ha.w) + hx.w;
        ep.x = eq4s(vb.x, t.x, c2la, al);
        ep.y = eq4s(vb.y, t.y, c2la, al);
        ep.z = eq4s(vb.z, t.z, c2la, al);
        ep.w = eq4s(vb.w, t.w, c2la, al);
        xe = vb; hm = hb; hc = hx; xc = vc;
    }

    // finish: given ec = eq4[r], produce eq7 row r-1 contribution into acc
    auto finish = [&](const float4 ec) {
        float4 p;
        p.x = ep.x + ec.x; p.y = ep.y + ec.y;
        p.z = ep.z + ec.z; p.w = ep.w + ec.w;
        float pn = __shfl_down(p.x, 1);
        if (lane == 63) pn = p.w;                  // replicate pad col 256
        float d0 = __fmaf_rn(p.x + p.y, 0.25f, 1e-8f);
        float d1 = __fmaf_rn(p.y + p.z, 0.25f, 1e-8f);
        float d2 = __fmaf_rn(p.z + p.w, 0.25f, 1e-8f);
        float d3 = __fmaf_rn(p.w + pn,  0.25f, 1e-8f);
        accx += xe.x * ep.x * __builtin_amdgcn_rcpf(d0)
              + xe.y * ep.y * __builtin_amdgcn_rcpf(d1);
        accy += xe.z * ep.z * __builtin_amdgcn_rcpf(d2)
              + xe.w * ep.w * __builtin_amdgcn_rcpf(d3);
    };

    // full step at input row r (r <= H-1): compute eq4[r], finish row r-1
    auto stepT = [&](int r) {
        float4 xn3 = loadrow(xp, r + 3, lane);     // prefetch (clamped), 3 deep
        float4 hn  = hblur(xn, lane);              // h[r+1]
        float4 t;
        t.x = __fmaf_rn(2.f, hc.x, hm.x) + hn.x;
        t.y = __fmaf_rn(2.f, hc.y, hm.y) + hn.y;
        t.z = __fmaf_rn(2.f, hc.z, hm.z) + hn.z;
        t.w = __fmaf_rn(2.f, hc.w, hm.w) + hn.w;
        float4 ec;
        ec.x = eq4s(xc.x, t.x, c2la, al);
        ec.y = eq4s(xc.y, t.y, c2la, al);
        ec.z = eq4s(xc.z, t.z, c2la, al);
        ec.w = eq4s(xc.w, t.w, c2la, al);
        finish(ec);
        hm = hc; hc = hn; xe = xc; xc = xn; xn = xn2; xn2 = xn3; ep = ec;
    };

    int r = r0 + 1;
    for (int orr = 0; orr < RH - 1; ++orr) {
        stepT(r); ++r;
        stepT(r); ++r;
        vfloat2 o; o.x = accx * 0.25f; o.y = accy * 0.25f;
        __builtin_nontemporal_store(o, reinterpret_cast<vfloat2*>(op));
        op += OW;
        accx = 0.f; accy = 0.f;
    }
    // last output row of the strip: second step may be eq4 row 256 -> replicate
    stepT(r); ++r;
    if (r <= H - 1) {
        stepT(r);
    } else {
        finish(ep);                                // ec := ep (bottom replicate)
    }
    vfloat2 o; o.x = accx * 0.25f; o.y = accy * 0.25f;
    __builtin_nontemporal_store(o, reinterpret_cast<vfloat2*>(op));
}

extern "C" void kernel_launch(void* const* d_in, const int* in_sizes, int n_in,
                              void* d_out, int out_size, void* d_ws, size_t ws_size,
                              hipStream_t stream) {
    const float* x     = (const float*)d_in[0];
    const float* lam   = (const float*)d_in[1];
    const float* alpha = (const float*)d_in[2];
    float* out = (float*)d_out;

    // 1024 planes x 8 strips of 16 output rows; 4 strips (waves) per block
    dim3 grid(2048, 1, 1);
    dim3 block(256, 1, 1);
    dp_rolling_kernel<<<grid, block, 0, stream>>>(x, lam, alpha, out);
}